// Round 1
// baseline (2479.894 us; speedup 1.0000x reference)
//
#include <hip/hip_runtime.h>
#include <hip/hip_bf16.h>

#define N_NODES 100000
#define N_EDGES 1600000
#define HDIM 128
#define NLAYERS 4
#define NGRAPH 256
#define ENCDIM 256
#define EPS_BN 1e-5f

// ---------------- CSR build ----------------
__global__ void k_count(const int* __restrict__ dst, int* __restrict__ cnt) {
    int e = blockIdx.x * 256 + threadIdx.x;
    if (e < N_EDGES) atomicAdd(&cnt[dst[e]], 1);
}

__global__ void k_dinv(const int* __restrict__ cnt, float* __restrict__ dinv) {
    int n = blockIdx.x * 256 + threadIdx.x;
    if (n < N_NODES) dinv[n] = rsqrtf((float)cnt[n] + 1.0f);
}

__global__ void k_scan_block(const int* __restrict__ cnt, int* __restrict__ excl,
                             int* __restrict__ bsums) {
    __shared__ int s[256];
    int t = threadIdx.x;
    int i = blockIdx.x * 256 + t;
    int v = (i < N_NODES) ? cnt[i] : 0;
    s[t] = v;
    __syncthreads();
    for (int off = 1; off < 256; off <<= 1) {
        int x = 0;
        if (t >= off) x = s[t - off];
        __syncthreads();
        if (t >= off) s[t] += x;
        __syncthreads();
    }
    if (i < N_NODES) excl[i] = s[t] - v;
    if (t == 255) bsums[blockIdx.x] = s[255];
}

__global__ void k_scan_sums(int* __restrict__ bsums, int nb) {
    __shared__ int s[512];
    int t = threadIdx.x;
    int v = (t < nb) ? bsums[t] : 0;
    s[t] = v;
    __syncthreads();
    for (int off = 1; off < 512; off <<= 1) {
        int x = 0;
        if (t >= off) x = s[t - off];
        __syncthreads();
        if (t >= off) s[t] += x;
        __syncthreads();
    }
    if (t < nb) bsums[t] = s[t] - v;
}

__global__ void k_scan_add(int* __restrict__ excl, const int* __restrict__ bsums,
                           int* __restrict__ cursor) {
    int i = blockIdx.x * 256 + threadIdx.x;
    if (i < N_NODES) {
        int v = excl[i] + bsums[blockIdx.x];
        excl[i] = v;
        cursor[i] = v;
    }
}

__global__ void k_scatter(const int* __restrict__ src, const int* __restrict__ dst,
                          const float* __restrict__ dinv, int* __restrict__ cursor,
                          int* __restrict__ csr_src, float* __restrict__ csr_w) {
    int e = blockIdx.x * 256 + threadIdx.x;
    if (e < N_EDGES) {
        int d = dst[e];
        int s = src[e];
        int p = atomicAdd(&cursor[d], 1);
        csr_src[p] = s;
        csr_w[p] = dinv[s] * dinv[d];
    }
}

// ---------------- GEMM: C[M x 128cols] (+)= X[M x 128] @ W[128 x (ldw cols)] ----
// colOff = blockIdx.y*128 selects a 128-wide column window of W / C.
// Tile: 32 rows x 128 cols per block, 256 threads, each thread 4x4 outputs.
template <int ACC>
__global__ __launch_bounds__(256) void k_gemm(const float* __restrict__ X,
                                              const float* __restrict__ W,
                                              float* __restrict__ C, int ldw, int ldc) {
    __shared__ float sW[128 * 128];
    __shared__ float sA[32 * 128];
    int t = threadIdx.x;
    int colOff = blockIdx.y * 128;

    float4* sW4 = (float4*)sW;
#pragma unroll
    for (int i = 0; i < 16; i++) {
        int idx = t + i * 256;          // 0..4095 float4s
        int r = idx >> 5;               // W row (k)
        int c4 = idx & 31;              // float4 within 128 cols
        sW4[idx] = *(const float4*)&W[(size_t)r * ldw + colOff + c4 * 4];
    }
    const float4* X4 = (const float4*)X + (size_t)blockIdx.x * 1024;  // 32*128/4
    float4* sA4 = (float4*)sA;
#pragma unroll
    for (int i = 0; i < 4; i++) sA4[t + i * 256] = X4[t + i * 256];
    __syncthreads();

    int cx = t & 31;    // col group: cols cx*4 .. cx*4+3
    int ry = t >> 5;    // row group: rows ry*4 .. ry*4+3
    float acc[4][4];
#pragma unroll
    for (int r = 0; r < 4; r++)
#pragma unroll
        for (int c = 0; c < 4; c++) acc[r][c] = 0.0f;

#pragma unroll 4
    for (int k = 0; k < 128; k++) {
        float4 w = sW4[k * 32 + cx];
#pragma unroll
        for (int r = 0; r < 4; r++) {
            float a = sA[(ry * 4 + r) * 128 + k];
            acc[r][0] = fmaf(a, w.x, acc[r][0]);
            acc[r][1] = fmaf(a, w.y, acc[r][1]);
            acc[r][2] = fmaf(a, w.z, acc[r][2]);
            acc[r][3] = fmaf(a, w.w, acc[r][3]);
        }
    }

    size_t rowBase = (size_t)blockIdx.x * 32;
#pragma unroll
    for (int r = 0; r < 4; r++) {
        size_t row = rowBase + ry * 4 + r;
        float* cp = &C[row * ldc + colOff + cx * 4];
        float4 v;
        v.x = acc[r][0]; v.y = acc[r][1]; v.z = acc[r][2]; v.w = acc[r][3];
        if (ACC) {
            float4 o = *(const float4*)cp;
            v.x += o.x; v.y += o.y; v.z += o.z; v.w += o.w;
        }
        *(float4*)cp = v;
    }
}

// ---------------- aggregation: out[n] = dinv[n]^2*hw[n] + sum_in csr_w*hw[src] + b
__global__ __launch_bounds__(256) void k_agg(const float* __restrict__ hw,
                                             const int* __restrict__ rs,
                                             const int* __restrict__ cnt,
                                             const int* __restrict__ csr_src,
                                             const float* __restrict__ csr_w,
                                             const float* __restrict__ dinv,
                                             const float* __restrict__ bias,
                                             float* __restrict__ out) {
    int n = blockIdx.x * 2 + (threadIdx.x >> 7);
    int f = threadIdx.x & 127;
    if (n >= N_NODES) return;
    float d = dinv[n];
    float acc = d * d * hw[(size_t)n * HDIM + f] + bias[f];
    int s0 = rs[n];
    int c = cnt[n];
    for (int e = 0; e < c; e++) {
        int s = csr_src[s0 + e];
        float w = csr_w[s0 + e];
        acc = fmaf(w, hw[(size_t)s * HDIM + f], acc);
    }
    out[(size_t)n * HDIM + f] = acc;
}

// ---------------- BN ----------------
__global__ __launch_bounds__(256) void k_bn_stats(const float* __restrict__ h,
                                                  float* __restrict__ sum,
                                                  float* __restrict__ sq) {
    int f = threadIdx.x & 127;
    int y = threadIdx.x >> 7;
    float s = 0.f, s2 = 0.f;
    for (int n = blockIdx.x * 2 + y; n < N_NODES; n += gridDim.x * 2) {
        float v = h[(size_t)n * HDIM + f];
        s += v;
        s2 = fmaf(v, v, s2);
    }
    __shared__ float ls[256], ls2[256];
    ls[threadIdx.x] = s;
    ls2[threadIdx.x] = s2;
    __syncthreads();
    if (y == 0) {
        atomicAdd(&sum[f], s + ls[128 + f]);
        atomicAdd(&sq[f], s2 + ls2[128 + f]);
    }
}

__global__ void k_bn_finalize(const float* __restrict__ sum, const float* __restrict__ sq,
                              const float* __restrict__ gamma, const float* __restrict__ beta,
                              float* __restrict__ scale, float* __restrict__ shift) {
    int f = threadIdx.x;
    float mu = sum[f] * (1.0f / N_NODES);
    float var = sq[f] * (1.0f / N_NODES) - mu * mu;
    float s = rsqrtf(var + EPS_BN) * gamma[f];
    scale[f] = s;
    shift[f] = beta[f] - mu * s;
}

__global__ __launch_bounds__(256) void k_bn_apply(float* __restrict__ h,
                                                  const float* __restrict__ scale,
                                                  const float* __restrict__ shift) {
    size_t i = (size_t)blockIdx.x * 256 + threadIdx.x;  // float4 index, 3.2M total
    float4 v = ((const float4*)h)[i];
    int f4 = ((int)i & 31) * 4;
    float4 sc = *(const float4*)&scale[f4];
    float4 sh = *(const float4*)&shift[f4];
    v.x = fmaxf(fmaf(v.x, sc.x, sh.x), 0.f);
    v.y = fmaxf(fmaf(v.y, sc.y, sh.y), 0.f);
    v.z = fmaxf(fmaf(v.z, sc.z, sh.z), 0.f);
    v.w = fmaxf(fmaf(v.w, sc.w, sh.w), 0.f);
    ((float4*)h)[i] = v;
}

// ---------------- pooling + decoder ----------------
__global__ void k_gcount(const int* __restrict__ batch, int* __restrict__ gcnt) {
    int n = blockIdx.x * 256 + threadIdx.x;
    if (n < N_NODES) atomicAdd(&gcnt[batch[n]], 1);
}

__global__ void k_gscan(const int* __restrict__ gcnt, int* __restrict__ gstart) {
    __shared__ int s[256];
    int t = threadIdx.x;
    int v = gcnt[t];
    s[t] = v;
    __syncthreads();
    for (int off = 1; off < 256; off <<= 1) {
        int x = 0;
        if (t >= off) x = s[t - off];
        __syncthreads();
        if (t >= off) s[t] += x;
        __syncthreads();
    }
    gstart[t] = s[t] - v;
}

__global__ __launch_bounds__(256) void k_pool(const float* __restrict__ encp,
                                              const float* __restrict__ eb,
                                              const int* __restrict__ gstart,
                                              const int* __restrict__ gcnt,
                                              float* __restrict__ pooled) {
    int g = blockIdx.x;
    int f = threadIdx.x;
    int s0 = gstart[g];
    int c = gcnt[g];
    float b = eb[f];
    float acc = 0.f;
    for (int i = 0; i < c; i++) {
        float v = encp[(size_t)(s0 + i) * ENCDIM + f] + b;
        acc += fmaxf(v, 0.f);
    }
    pooled[g * ENCDIM + f] = acc / fmaxf((float)c, 1.0f);
}

__global__ __launch_bounds__(128) void k_dec(const float* __restrict__ pooled,
                                             const float* __restrict__ W1,
                                             const float* __restrict__ b1,
                                             const float* __restrict__ W2,
                                             const float* __restrict__ b2,
                                             float* __restrict__ out) {
    int g = blockIdx.x;
    int j = threadIdx.x;
    const float* p = &pooled[g * ENCDIM];
    float acc = b1[j];
    for (int k = 0; k < ENCDIM; k++) acc = fmaf(p[k], W1[k * 128 + j], acc);
    float h = fmaxf(acc, 0.f) * W2[j];
    for (int off = 32; off; off >>= 1) h += __shfl_down(h, off);
    __shared__ float red[2];
    if ((j & 63) == 0) red[j >> 6] = h;
    __syncthreads();
    if (j == 0) out[g] = red[0] + red[1] + b2[0];
}

extern "C" void kernel_launch(void* const* d_in, const int* in_sizes, int n_in,
                              void* d_out, int out_size, void* d_ws, size_t ws_size,
                              hipStream_t stream) {
    const float* x = (const float*)d_in[0];
    const int* ei = (const int*)d_in[1];
    const int* src = ei;
    const int* dst = ei + N_EDGES;
    const int* batch = (const int*)d_in[2];
    const float* convW = (const float*)d_in[3];
    const float* convB = (const float*)d_in[4];
    const float* gamma = (const float*)d_in[5];
    const float* beta = (const float*)d_in[6];
    const float* encW = (const float*)d_in[7];
    const float* encB = (const float*)d_in[8];
    const float* dW1 = (const float*)d_in[9];
    const float* db1 = (const float*)d_in[10];
    const float* dW2 = (const float*)d_in[11];
    const float* db2 = (const float*)d_in[12];
    float* out = (float*)d_out;

    char* w = (char*)d_ws;
    auto alloc = [&](size_t bytes) {
        char* p = w;
        w += (bytes + 255) & ~(size_t)255;
        return p;
    };
    int* cnt = (int*)alloc((size_t)N_NODES * 4);
    int* rs = (int*)alloc((size_t)N_NODES * 4);
    int* cursor = (int*)alloc((size_t)N_NODES * 4);
    int* bsums = (int*)alloc(512 * 4);
    float* dinv = (float*)alloc((size_t)N_NODES * 4);
    int* csr_src = (int*)alloc((size_t)N_EDGES * 4);
    float* csr_w = (float*)alloc((size_t)N_EDGES * 4);
    float* A = (float*)alloc((size_t)N_NODES * HDIM * 4);      // layer act
    float* B = (float*)alloc((size_t)N_NODES * HDIM * 4);      // hw scratch
    float* encp = (float*)alloc((size_t)N_NODES * ENCDIM * 4); // encoder pre-act
    float* bnsum = (float*)alloc(128 * 4);
    float* bnsq = (float*)alloc(128 * 4);
    float* bnscale = (float*)alloc(128 * 4);
    float* bnshift = (float*)alloc(128 * 4);
    int* gcnt = (int*)alloc(256 * 4);
    int* gstart = (int*)alloc(256 * 4);
    float* pooled = (float*)alloc(256 * 256 * 4);

    // CSR build + degree normalization
    hipMemsetAsync(cnt, 0, (size_t)N_NODES * 4, stream);
    k_count<<<(N_EDGES + 255) / 256, 256, 0, stream>>>(dst, cnt);
    k_dinv<<<(N_NODES + 255) / 256, 256, 0, stream>>>(cnt, dinv);
    int nb = (N_NODES + 255) / 256;  // 391
    k_scan_block<<<nb, 256, 0, stream>>>(cnt, rs, bsums);
    k_scan_sums<<<1, 512, 0, stream>>>(bsums, nb);
    k_scan_add<<<nb, 256, 0, stream>>>(rs, bsums, cursor);
    k_scatter<<<(N_EDGES + 255) / 256, 256, 0, stream>>>(src, dst, dinv, cursor,
                                                         csr_src, csr_w);

    const float* hin = x;
    for (int l = 0; l < NLAYERS; l++) {
        // hw = h @ W_l
        k_gemm<0><<<dim3(3125, 1), 256, 0, stream>>>(hin, convW + (size_t)l * 128 * 128,
                                                     B, 128, 128);
        // aggregate (+bias)
        k_agg<<<N_NODES / 2, 256, 0, stream>>>(B, rs, cnt, csr_src, csr_w, dinv,
                                               convB + l * 128, A);
        // BN + ReLU (in place on A)
        hipMemsetAsync(bnsum, 0, 128 * 4, stream);
        hipMemsetAsync(bnsq, 0, 128 * 4, stream);
        k_bn_stats<<<512, 256, 0, stream>>>(A, bnsum, bnsq);
        k_bn_finalize<<<1, 128, 0, stream>>>(bnsum, bnsq, gamma + l * 128, beta + l * 128,
                                             bnscale, bnshift);
        k_bn_apply<<<12500, 256, 0, stream>>>(A, bnscale, bnshift);
        // encoder accumulate: encp (+)= A @ encW[l*128 : (l+1)*128, :]
        if (l == 0)
            k_gemm<0><<<dim3(3125, 2), 256, 0, stream>>>(A, encW + (size_t)l * 128 * 256,
                                                         encp, 256, 256);
        else
            k_gemm<1><<<dim3(3125, 2), 256, 0, stream>>>(A, encW + (size_t)l * 128 * 256,
                                                         encp, 256, 256);
        hin = A;
    }

    // pooling (batch is sorted)
    hipMemsetAsync(gcnt, 0, 256 * 4, stream);
    k_gcount<<<(N_NODES + 255) / 256, 256, 0, stream>>>(batch, gcnt);
    k_gscan<<<1, 256, 0, stream>>>(gcnt, gstart);
    k_pool<<<256, 256, 0, stream>>>(encp, encB, gstart, gcnt, pooled);
    k_dec<<<256, 128, 0, stream>>>(pooled, dW1, db1, dW2, db2, out);
}

// Round 2
// 2161.821 us; speedup vs baseline: 1.1471x; 1.1471x over previous
//
#include <hip/hip_runtime.h>
#include <hip/hip_bf16.h>

#define N_NODES 100000
#define N_EDGES 1600000
#define HDIM 128
#define NLAYERS 4
#define NGRAPH 256
#define ENCDIM 256
#define EPS_BN 1e-5f

// ---------------- CSR build ----------------
__global__ void k_count(const int* __restrict__ dst, int* __restrict__ cnt) {
    int e = blockIdx.x * 256 + threadIdx.x;
    if (e < N_EDGES) atomicAdd(&cnt[dst[e]], 1);
}

__global__ void k_dinv(const int* __restrict__ cnt, float* __restrict__ dinv) {
    int n = blockIdx.x * 256 + threadIdx.x;
    if (n < N_NODES) dinv[n] = rsqrtf((float)cnt[n] + 1.0f);
}

__global__ void k_scan_block(const int* __restrict__ cnt, int* __restrict__ excl,
                             int* __restrict__ bsums) {
    __shared__ int s[256];
    int t = threadIdx.x;
    int i = blockIdx.x * 256 + t;
    int v = (i < N_NODES) ? cnt[i] : 0;
    s[t] = v;
    __syncthreads();
    for (int off = 1; off < 256; off <<= 1) {
        int x = 0;
        if (t >= off) x = s[t - off];
        __syncthreads();
        if (t >= off) s[t] += x;
        __syncthreads();
    }
    if (i < N_NODES) excl[i] = s[t] - v;
    if (t == 255) bsums[blockIdx.x] = s[255];
}

__global__ void k_scan_sums(int* __restrict__ bsums, int nb) {
    __shared__ int s[512];
    int t = threadIdx.x;
    int v = (t < nb) ? bsums[t] : 0;
    s[t] = v;
    __syncthreads();
    for (int off = 1; off < 512; off <<= 1) {
        int x = 0;
        if (t >= off) x = s[t - off];
        __syncthreads();
        if (t >= off) s[t] += x;
        __syncthreads();
    }
    if (t < nb) bsums[t] = s[t] - v;
}

__global__ void k_scan_add(int* __restrict__ excl, const int* __restrict__ bsums,
                           int* __restrict__ cursor) {
    int i = blockIdx.x * 256 + threadIdx.x;
    if (i < N_NODES) {
        int v = excl[i] + bsums[blockIdx.x];
        excl[i] = v;
        cursor[i] = v;
    }
}

// packed edge list: (src, weight) interleaved, 8B per edge
__global__ void k_scatter(const int* __restrict__ src, const int* __restrict__ dst,
                          const float* __restrict__ dinv, int* __restrict__ cursor,
                          int2* __restrict__ csr_ew) {
    int e = blockIdx.x * 256 + threadIdx.x;
    if (e < N_EDGES) {
        int d = dst[e];
        int s = src[e];
        int p = atomicAdd(&cursor[d], 1);
        int2 v;
        v.x = s;
        v.y = __float_as_int(dinv[s] * dinv[d]);
        csr_ew[p] = v;
    }
}

// ---------------- GEMM: C[M x 128cols] (+)= X[M x 128] @ W[128 x (ldw cols)] ----
// Tile: 32 rows x 128 cols per block, 256 threads, each thread 4x4 outputs.
// Inner loop chunks K by 4: all LDS reads are b128 (A reads wave-broadcast,
// W reads 512B contiguous) -> 8 ds_read_b128 per 64 FMA -> VALU-bound.
template <int ACC>
__global__ __launch_bounds__(256) void k_gemm(const float* __restrict__ X,
                                              const float* __restrict__ W,
                                              float* __restrict__ C, int ldw, int ldc) {
    __shared__ float sW[128 * 128];
    __shared__ float sA[32 * 128];
    int t = threadIdx.x;
    int colOff = blockIdx.y * 128;

    float4* sW4 = (float4*)sW;
#pragma unroll
    for (int i = 0; i < 16; i++) {
        int idx = t + i * 256;          // 0..4095 float4s
        int r = idx >> 5;               // W row (k)
        int c4 = idx & 31;              // float4 within 128 cols
        sW4[idx] = *(const float4*)&W[(size_t)r * ldw + colOff + c4 * 4];
    }
    const float4* X4 = (const float4*)X + (size_t)blockIdx.x * 1024;  // 32*128/4
    float4* sA4 = (float4*)sA;
#pragma unroll
    for (int i = 0; i < 4; i++) sA4[t + i * 256] = X4[t + i * 256];
    __syncthreads();

    int cx = t & 31;    // col group: cols cx*4 .. cx*4+3
    int ry = t >> 5;    // row group: rows ry*4 .. ry*4+3
    float acc[4][4];
#pragma unroll
    for (int r = 0; r < 4; r++)
#pragma unroll
        for (int c = 0; c < 4; c++) acc[r][c] = 0.0f;

#pragma unroll 8
    for (int k4 = 0; k4 < 32; k4++) {
        float4 a[4], w[4];
#pragma unroll
        for (int r = 0; r < 4; r++) a[r] = sA4[(ry * 4 + r) * 32 + k4];
#pragma unroll
        for (int j = 0; j < 4; j++) w[j] = sW4[(k4 * 4 + j) * 32 + cx];
#pragma unroll
        for (int r = 0; r < 4; r++) {
            acc[r][0] = fmaf(a[r].x, w[0].x, acc[r][0]);
            acc[r][1] = fmaf(a[r].x, w[0].y, acc[r][1]);
            acc[r][2] = fmaf(a[r].x, w[0].z, acc[r][2]);
            acc[r][3] = fmaf(a[r].x, w[0].w, acc[r][3]);
            acc[r][0] = fmaf(a[r].y, w[1].x, acc[r][0]);
            acc[r][1] = fmaf(a[r].y, w[1].y, acc[r][1]);
            acc[r][2] = fmaf(a[r].y, w[1].z, acc[r][2]);
            acc[r][3] = fmaf(a[r].y, w[1].w, acc[r][3]);
            acc[r][0] = fmaf(a[r].z, w[2].x, acc[r][0]);
            acc[r][1] = fmaf(a[r].z, w[2].y, acc[r][1]);
            acc[r][2] = fmaf(a[r].z, w[2].z, acc[r][2]);
            acc[r][3] = fmaf(a[r].z, w[2].w, acc[r][3]);
            acc[r][0] = fmaf(a[r].w, w[3].x, acc[r][0]);
            acc[r][1] = fmaf(a[r].w, w[3].y, acc[r][1]);
            acc[r][2] = fmaf(a[r].w, w[3].z, acc[r][2]);
            acc[r][3] = fmaf(a[r].w, w[3].w, acc[r][3]);
        }
    }

    size_t rowBase = (size_t)blockIdx.x * 32;
#pragma unroll
    for (int r = 0; r < 4; r++) {
        size_t row = rowBase + ry * 4 + r;
        float* cp = &C[row * ldc + colOff + cx * 4];
        float4 v;
        v.x = acc[r][0]; v.y = acc[r][1]; v.z = acc[r][2]; v.w = acc[r][3];
        if (ACC) {
            float4 o = *(const float4*)cp;
            v.x += o.x; v.y += o.y; v.z += o.z; v.w += o.w;
        }
        *(float4*)cp = v;
    }
}

// ---------------- aggregation: out[n] = dinv[n]^2*hw[n] + sum_in w*hw[src] + b
// 8 nodes per block; 32 lanes x float4 per node; edge loop unrolled by 4 so
// 4 independent 16B gathers are in flight per lane.
__global__ __launch_bounds__(256) void k_agg(const float4* __restrict__ hw4,
                                             const int* __restrict__ rs,
                                             const int* __restrict__ cnt,
                                             const int2* __restrict__ csr_ew,
                                             const float* __restrict__ dinv,
                                             const float4* __restrict__ bias4,
                                             float4* __restrict__ out4) {
    int n = blockIdx.x * 8 + (threadIdx.x >> 5);
    int lane = threadIdx.x & 31;
    if (n >= N_NODES) return;
    float d = dinv[n];
    float dd = d * d;
    float4 self = hw4[(size_t)n * 32 + lane];
    float4 b = bias4[lane];
    float4 acc;
    acc.x = fmaf(dd, self.x, b.x);
    acc.y = fmaf(dd, self.y, b.y);
    acc.z = fmaf(dd, self.z, b.z);
    acc.w = fmaf(dd, self.w, b.w);
    int s0 = rs[n];
    int c = cnt[n];
    int e = 0;
    for (; e + 4 <= c; e += 4) {
        int2 e0 = csr_ew[s0 + e];
        int2 e1 = csr_ew[s0 + e + 1];
        int2 e2 = csr_ew[s0 + e + 2];
        int2 e3 = csr_ew[s0 + e + 3];
        float4 v0 = hw4[(size_t)e0.x * 32 + lane];
        float4 v1 = hw4[(size_t)e1.x * 32 + lane];
        float4 v2 = hw4[(size_t)e2.x * 32 + lane];
        float4 v3 = hw4[(size_t)e3.x * 32 + lane];
        float w0 = __int_as_float(e0.y);
        float w1 = __int_as_float(e1.y);
        float w2 = __int_as_float(e2.y);
        float w3 = __int_as_float(e3.y);
        acc.x = fmaf(w0, v0.x, acc.x); acc.y = fmaf(w0, v0.y, acc.y);
        acc.z = fmaf(w0, v0.z, acc.z); acc.w = fmaf(w0, v0.w, acc.w);
        acc.x = fmaf(w1, v1.x, acc.x); acc.y = fmaf(w1, v1.y, acc.y);
        acc.z = fmaf(w1, v1.z, acc.z); acc.w = fmaf(w1, v1.w, acc.w);
        acc.x = fmaf(w2, v2.x, acc.x); acc.y = fmaf(w2, v2.y, acc.y);
        acc.z = fmaf(w2, v2.z, acc.z); acc.w = fmaf(w2, v2.w, acc.w);
        acc.x = fmaf(w3, v3.x, acc.x); acc.y = fmaf(w3, v3.y, acc.y);
        acc.z = fmaf(w3, v3.z, acc.z); acc.w = fmaf(w3, v3.w, acc.w);
    }
    for (; e < c; e++) {
        int2 ee = csr_ew[s0 + e];
        float4 v = hw4[(size_t)ee.x * 32 + lane];
        float w = __int_as_float(ee.y);
        acc.x = fmaf(w, v.x, acc.x); acc.y = fmaf(w, v.y, acc.y);
        acc.z = fmaf(w, v.z, acc.z); acc.w = fmaf(w, v.w, acc.w);
    }
    out4[(size_t)n * 32 + lane] = acc;
}

// ---------------- BN ----------------
__global__ __launch_bounds__(256) void k_bn_stats(const float* __restrict__ h,
                                                  float* __restrict__ sum,
                                                  float* __restrict__ sq) {
    int f = threadIdx.x & 127;
    int y = threadIdx.x >> 7;
    float s = 0.f, s2 = 0.f;
    for (int n = blockIdx.x * 2 + y; n < N_NODES; n += gridDim.x * 2) {
        float v = h[(size_t)n * HDIM + f];
        s += v;
        s2 = fmaf(v, v, s2);
    }
    __shared__ float ls[256], ls2[256];
    ls[threadIdx.x] = s;
    ls2[threadIdx.x] = s2;
    __syncthreads();
    if (y == 0) {
        atomicAdd(&sum[f], s + ls[128 + f]);
        atomicAdd(&sq[f], s2 + ls2[128 + f]);
    }
}

__global__ void k_bn_finalize(const float* __restrict__ sum, const float* __restrict__ sq,
                              const float* __restrict__ gamma, const float* __restrict__ beta,
                              float* __restrict__ scale, float* __restrict__ shift) {
    int f = threadIdx.x;
    float mu = sum[f] * (1.0f / N_NODES);
    float var = sq[f] * (1.0f / N_NODES) - mu * mu;
    float s = rsqrtf(var + EPS_BN) * gamma[f];
    scale[f] = s;
    shift[f] = beta[f] - mu * s;
}

__global__ __launch_bounds__(256) void k_bn_apply(float* __restrict__ h,
                                                  const float* __restrict__ scale,
                                                  const float* __restrict__ shift) {
    size_t i = (size_t)blockIdx.x * 256 + threadIdx.x;  // float4 index, 3.2M total
    float4 v = ((const float4*)h)[i];
    int f4 = ((int)i & 31) * 4;
    float4 sc = *(const float4*)&scale[f4];
    float4 sh = *(const float4*)&shift[f4];
    v.x = fmaxf(fmaf(v.x, sc.x, sh.x), 0.f);
    v.y = fmaxf(fmaf(v.y, sc.y, sh.y), 0.f);
    v.z = fmaxf(fmaf(v.z, sc.z, sh.z), 0.f);
    v.w = fmaxf(fmaf(v.w, sc.w, sh.w), 0.f);
    ((float4*)h)[i] = v;
}

// ---------------- pooling + decoder ----------------
__global__ void k_gcount(const int* __restrict__ batch, int* __restrict__ gcnt) {
    int n = blockIdx.x * 256 + threadIdx.x;
    if (n < N_NODES) atomicAdd(&gcnt[batch[n]], 1);
}

__global__ void k_gscan(const int* __restrict__ gcnt, int* __restrict__ gstart) {
    __shared__ int s[256];
    int t = threadIdx.x;
    int v = gcnt[t];
    s[t] = v;
    __syncthreads();
    for (int off = 1; off < 256; off <<= 1) {
        int x = 0;
        if (t >= off) x = s[t - off];
        __syncthreads();
        if (t >= off) s[t] += x;
        __syncthreads();
    }
    gstart[t] = s[t] - v;
}

__global__ __launch_bounds__(256) void k_pool(const float* __restrict__ encp,
                                              const float* __restrict__ eb,
                                              const int* __restrict__ gstart,
                                              const int* __restrict__ gcnt,
                                              float* __restrict__ pooled) {
    int g = blockIdx.x;
    int f = threadIdx.x;
    int s0 = gstart[g];
    int c = gcnt[g];
    float b = eb[f];
    float acc = 0.f;
    for (int i = 0; i < c; i++) {
        float v = encp[(size_t)(s0 + i) * ENCDIM + f] + b;
        acc += fmaxf(v, 0.f);
    }
    pooled[g * ENCDIM + f] = acc / fmaxf((float)c, 1.0f);
}

__global__ __launch_bounds__(128) void k_dec(const float* __restrict__ pooled,
                                             const float* __restrict__ W1,
                                             const float* __restrict__ b1,
                                             const float* __restrict__ W2,
                                             const float* __restrict__ b2,
                                             float* __restrict__ out) {
    int g = blockIdx.x;
    int j = threadIdx.x;
    const float* p = &pooled[g * ENCDIM];
    float acc = b1[j];
    for (int k = 0; k < ENCDIM; k++) acc = fmaf(p[k], W1[k * 128 + j], acc);
    float h = fmaxf(acc, 0.f) * W2[j];
    for (int off = 32; off; off >>= 1) h += __shfl_down(h, off);
    __shared__ float red[2];
    if ((j & 63) == 0) red[j >> 6] = h;
    __syncthreads();
    if (j == 0) out[g] = red[0] + red[1] + b2[0];
}

extern "C" void kernel_launch(void* const* d_in, const int* in_sizes, int n_in,
                              void* d_out, int out_size, void* d_ws, size_t ws_size,
                              hipStream_t stream) {
    const float* x = (const float*)d_in[0];
    const int* ei = (const int*)d_in[1];
    const int* src = ei;
    const int* dst = ei + N_EDGES;
    const int* batch = (const int*)d_in[2];
    const float* convW = (const float*)d_in[3];
    const float* convB = (const float*)d_in[4];
    const float* gamma = (const float*)d_in[5];
    const float* beta = (const float*)d_in[6];
    const float* encW = (const float*)d_in[7];
    const float* encB = (const float*)d_in[8];
    const float* dW1 = (const float*)d_in[9];
    const float* db1 = (const float*)d_in[10];
    const float* dW2 = (const float*)d_in[11];
    const float* db2 = (const float*)d_in[12];
    float* out = (float*)d_out;

    char* w = (char*)d_ws;
    auto alloc = [&](size_t bytes) {
        char* p = w;
        w += (bytes + 255) & ~(size_t)255;
        return p;
    };
    int* cnt = (int*)alloc((size_t)N_NODES * 4);
    int* rs = (int*)alloc((size_t)N_NODES * 4);
    int* cursor = (int*)alloc((size_t)N_NODES * 4);
    int* bsums = (int*)alloc(512 * 4);
    float* dinv = (float*)alloc((size_t)N_NODES * 4);
    int2* csr_ew = (int2*)alloc((size_t)N_EDGES * 8);
    float* A = (float*)alloc((size_t)N_NODES * HDIM * 4);      // layer act
    float* B = (float*)alloc((size_t)N_NODES * HDIM * 4);      // hw scratch
    float* encp = (float*)alloc((size_t)N_NODES * ENCDIM * 4); // encoder pre-act
    float* bnsum = (float*)alloc(128 * 4);
    float* bnsq = (float*)alloc(128 * 4);
    float* bnscale = (float*)alloc(128 * 4);
    float* bnshift = (float*)alloc(128 * 4);
    int* gcnt = (int*)alloc(256 * 4);
    int* gstart = (int*)alloc(256 * 4);
    float* pooled = (float*)alloc(256 * 256 * 4);

    // CSR build + degree normalization
    hipMemsetAsync(cnt, 0, (size_t)N_NODES * 4, stream);
    k_count<<<(N_EDGES + 255) / 256, 256, 0, stream>>>(dst, cnt);
    k_dinv<<<(N_NODES + 255) / 256, 256, 0, stream>>>(cnt, dinv);
    int nb = (N_NODES + 255) / 256;  // 391
    k_scan_block<<<nb, 256, 0, stream>>>(cnt, rs, bsums);
    k_scan_sums<<<1, 512, 0, stream>>>(bsums, nb);
    k_scan_add<<<nb, 256, 0, stream>>>(rs, bsums, cursor);
    k_scatter<<<(N_EDGES + 255) / 256, 256, 0, stream>>>(src, dst, dinv, cursor, csr_ew);

    const float* hin = x;
    for (int l = 0; l < NLAYERS; l++) {
        // hw = h @ W_l
        k_gemm<0><<<dim3(3125, 1), 256, 0, stream>>>(hin, convW + (size_t)l * 128 * 128,
                                                     B, 128, 128);
        // aggregate (+bias)
        k_agg<<<N_NODES / 8, 256, 0, stream>>>((const float4*)B, rs, cnt, csr_ew, dinv,
                                               (const float4*)(convB + l * 128),
                                               (float4*)A);
        // BN + ReLU (in place on A)
        hipMemsetAsync(bnsum, 0, 128 * 4, stream);
        hipMemsetAsync(bnsq, 0, 128 * 4, stream);
        k_bn_stats<<<512, 256, 0, stream>>>(A, bnsum, bnsq);
        k_bn_finalize<<<1, 128, 0, stream>>>(bnsum, bnsq, gamma + l * 128, beta + l * 128,
                                             bnscale, bnshift);
        k_bn_apply<<<12500, 256, 0, stream>>>(A, bnscale, bnshift);
        // encoder accumulate: encp (+)= A @ encW[l*128 : (l+1)*128, :]
        if (l == 0)
            k_gemm<0><<<dim3(3125, 2), 256, 0, stream>>>(A, encW + (size_t)l * 128 * 256,
                                                         encp, 256, 256);
        else
            k_gemm<1><<<dim3(3125, 2), 256, 0, stream>>>(A, encW + (size_t)l * 128 * 256,
                                                         encp, 256, 256);
        hin = A;
    }

    // pooling (batch is sorted)
    hipMemsetAsync(gcnt, 0, 256 * 4, stream);
    k_gcount<<<(N_NODES + 255) / 256, 256, 0, stream>>>(batch, gcnt);
    k_gscan<<<1, 256, 0, stream>>>(gcnt, gstart);
    k_pool<<<256, 256, 0, stream>>>(encp, encB, gstart, gcnt, pooled);
    k_dec<<<256, 128, 0, stream>>>(pooled, dW1, db1, dW2, db2, out);
}

// Round 3
// 1680.047 us; speedup vs baseline: 1.4761x; 1.2868x over previous
//
#include <hip/hip_runtime.h>
#include <hip/hip_bf16.h>

#define N_NODES 100000
#define NPAD    100096   // 782 * 128
#define N_EDGES 1600000
#define HDIM 128
#define NLAYERS 4
#define NGRAPH 256
#define ENCDIM 256
#define EPS_BN 1e-5f

typedef __attribute__((ext_vector_type(8))) short bf16x8;
typedef __attribute__((ext_vector_type(4))) float f32x4;

__device__ __forceinline__ unsigned short f2bf(float v) {
    unsigned int u = __float_as_uint(v);
    u += 0x7FFFu + ((u >> 16) & 1u);
    return (unsigned short)(u >> 16);
}
__device__ __forceinline__ float bf2f(unsigned int lo16) {
    return __uint_as_float(lo16 << 16);
}

// ---------------- CSR build ----------------
__global__ void k_count(const int* __restrict__ dst, int* __restrict__ cnt) {
    int e = blockIdx.x * 256 + threadIdx.x;
    if (e < N_EDGES) atomicAdd(&cnt[dst[e]], 1);
}

__global__ void k_dinv(const int* __restrict__ cnt, float* __restrict__ dinv) {
    int n = blockIdx.x * 256 + threadIdx.x;
    if (n < N_NODES) dinv[n] = rsqrtf((float)cnt[n] + 1.0f);
}

__global__ void k_scan_block(const int* __restrict__ cnt, int* __restrict__ excl,
                             int* __restrict__ bsums) {
    __shared__ int s[256];
    int t = threadIdx.x;
    int i = blockIdx.x * 256 + t;
    int v = (i < N_NODES) ? cnt[i] : 0;
    s[t] = v;
    __syncthreads();
    for (int off = 1; off < 256; off <<= 1) {
        int x = 0;
        if (t >= off) x = s[t - off];
        __syncthreads();
        if (t >= off) s[t] += x;
        __syncthreads();
    }
    if (i < N_NODES) excl[i] = s[t] - v;
    if (t == 255) bsums[blockIdx.x] = s[255];
}

__global__ void k_scan_sums(int* __restrict__ bsums, int nb) {
    __shared__ int s[512];
    int t = threadIdx.x;
    int v = (t < nb) ? bsums[t] : 0;
    s[t] = v;
    __syncthreads();
    for (int off = 1; off < 512; off <<= 1) {
        int x = 0;
        if (t >= off) x = s[t - off];
        __syncthreads();
        if (t >= off) s[t] += x;
        __syncthreads();
    }
    if (t < nb) bsums[t] = s[t] - v;
}

__global__ void k_scan_add(int* __restrict__ excl, const int* __restrict__ bsums,
                           int* __restrict__ cursor) {
    int i = blockIdx.x * 256 + threadIdx.x;
    if (i < N_NODES) {
        int v = excl[i] + bsums[blockIdx.x];
        excl[i] = v;
        cursor[i] = v;
    }
}

__global__ void k_scatter(const int* __restrict__ src, const int* __restrict__ dst,
                          const float* __restrict__ dinv, int* __restrict__ cursor,
                          int2* __restrict__ csr_ew) {
    int e = blockIdx.x * 256 + threadIdx.x;
    if (e < N_EDGES) {
        int d = dst[e];
        int s = src[e];
        int p = atomicAdd(&cursor[d], 1);
        int2 v;
        v.x = s;
        v.y = __float_as_int(dinv[s] * dinv[d]);
        csr_ew[p] = v;
    }
}

// ---------------- weight -> MFMA B-fragment order, split hi/lo ----------------
// Frag layout: F[((nt*4 + ks)*64 + lane)*8 + j] = W[(ks*32 + (lane>>4)*8 + j)*ldw
//                                                   + nt*16 + (lane&15)]
__global__ void k_wfrag(const float* __restrict__ W, int ldw, int ntiles,
                        unsigned short* __restrict__ Fh, unsigned short* __restrict__ Fl) {
    int t = blockIdx.x * 256 + threadIdx.x;
    if (t >= ntiles * 256) return;
    int lane = t & 63, ks = (t >> 6) & 3, nt = t >> 8;
    int r16 = lane & 15, kq = lane >> 4;
    ushort4 h0, h1, l0, l1;
    unsigned short h[8], l[8];
#pragma unroll
    for (int j = 0; j < 8; j++) {
        float w = W[(size_t)(ks * 32 + kq * 8 + j) * ldw + nt * 16 + r16];
        unsigned short hh = f2bf(w);
        h[j] = hh;
        l[j] = f2bf(w - bf2f(hh));
    }
    h0 = make_ushort4(h[0], h[1], h[2], h[3]);
    h1 = make_ushort4(h[4], h[5], h[6], h[7]);
    l0 = make_ushort4(l[0], l[1], l[2], l[3]);
    l1 = make_ushort4(l[4], l[5], l[6], l[7]);
    ((ushort4*)(Fh + (size_t)t * 8))[0] = h0;
    ((ushort4*)(Fh + (size_t)t * 8))[1] = h1;
    ((ushort4*)(Fl + (size_t)t * 8))[0] = l0;
    ((ushort4*)(Fl + (size_t)t * 8))[1] = l1;
}

// ---------------- x -> hi/lo bf16 (with pad zeroing) ----------------
__global__ __launch_bounds__(256) void k_split_x(const float4* __restrict__ x4,
                                                 ushort4* __restrict__ Uh4,
                                                 ushort4* __restrict__ Ul4) {
    size_t i = (size_t)blockIdx.x * 256 + threadIdx.x;  // NPAD*32 float4s
    size_t row = i >> 5;
    float4 v = make_float4(0.f, 0.f, 0.f, 0.f);
    if (row < N_NODES) v = x4[i];
    ushort4 h, l;
    h.x = f2bf(v.x); l.x = f2bf(v.x - bf2f(h.x));
    h.y = f2bf(v.y); l.y = f2bf(v.y - bf2f(h.y));
    h.z = f2bf(v.z); l.z = f2bf(v.z - bf2f(h.z));
    h.w = f2bf(v.w); l.w = f2bf(v.w - bf2f(h.w));
    Uh4[i] = h;
    Ul4[i] = l;
}

// ---------------- split-bf16 MFMA GEMM ----------------
// C[NPAD x ldc cols, panel colOff..colOff+127] (+)= (Ah+Al)[NPAD x 128] @ W
// Block: 256 thr / 4 waves; wave owns 32 rows; M-tile 128/block; N panel 128.
template <int ACC>
__global__ __launch_bounds__(256) void k_mfma(const unsigned short* __restrict__ Ah,
                                              const unsigned short* __restrict__ Al,
                                              const unsigned short* __restrict__ Fh,
                                              const unsigned short* __restrict__ Fl,
                                              float* __restrict__ C, int ldc) {
    int lane = threadIdx.x & 63;
    int wid = threadIdx.x >> 6;
    int r16 = lane & 15, kq = lane >> 4;
    size_t mrow0 = (size_t)blockIdx.x * 128 + wid * 32;
    int colOff = blockIdx.y * 128;
    int ntBase = blockIdx.y * 8;

    bf16x8 ah[2][4], al[2][4];
#pragma unroll
    for (int mt = 0; mt < 2; mt++) {
        const unsigned short* pa = Ah + (mrow0 + mt * 16 + r16) * 128 + kq * 8;
        const unsigned short* pl = Al + (mrow0 + mt * 16 + r16) * 128 + kq * 8;
#pragma unroll
        for (int ks = 0; ks < 4; ks++) {
            ah[mt][ks] = *reinterpret_cast<const bf16x8*>(pa + ks * 32);
            al[mt][ks] = *reinterpret_cast<const bf16x8*>(pl + ks * 32);
        }
    }

    f32x4 acc[2][8];
#pragma unroll
    for (int mt = 0; mt < 2; mt++)
#pragma unroll
        for (int nt = 0; nt < 8; nt++) acc[mt][nt] = (f32x4){0.f, 0.f, 0.f, 0.f};

#pragma unroll
    for (int nt = 0; nt < 8; nt++) {
        const unsigned short* pbh = Fh + ((size_t)(ntBase + nt) * 4 * 64 + lane) * 8;
        const unsigned short* pbl = Fl + ((size_t)(ntBase + nt) * 4 * 64 + lane) * 8;
        bf16x8 bh[4], bl[4];
#pragma unroll
        for (int ks = 0; ks < 4; ks++) {
            bh[ks] = *reinterpret_cast<const bf16x8*>(pbh + ks * 512);
            bl[ks] = *reinterpret_cast<const bf16x8*>(pbl + ks * 512);
        }
#pragma unroll
        for (int mt = 0; mt < 2; mt++)
#pragma unroll
            for (int ks = 0; ks < 4; ks++) {
                acc[mt][nt] = __builtin_amdgcn_mfma_f32_16x16x32_bf16(ah[mt][ks], bl[ks],
                                                                     acc[mt][nt], 0, 0, 0);
                acc[mt][nt] = __builtin_amdgcn_mfma_f32_16x16x32_bf16(al[mt][ks], bh[ks],
                                                                     acc[mt][nt], 0, 0, 0);
                acc[mt][nt] = __builtin_amdgcn_mfma_f32_16x16x32_bf16(ah[mt][ks], bh[ks],
                                                                     acc[mt][nt], 0, 0, 0);
            }
    }

#pragma unroll
    for (int mt = 0; mt < 2; mt++)
#pragma unroll
        for (int nt = 0; nt < 8; nt++)
#pragma unroll
            for (int r = 0; r < 4; r++) {
                size_t row = mrow0 + mt * 16 + kq * 4 + r;
                float* cp = C + row * ldc + colOff + nt * 16 + r16;
                float v = acc[mt][nt][r];
                if (ACC) v += *cp;
                *cp = v;
            }
}

// ---------------- aggregation: U(pair) <- S * hw + bias ----------------
__global__ __launch_bounds__(256) void k_agg(const float4* __restrict__ hw4,
                                             const int* __restrict__ rs,
                                             const int* __restrict__ cnt,
                                             const int2* __restrict__ csr_ew,
                                             const float* __restrict__ dinv,
                                             const float4* __restrict__ bias4,
                                             unsigned short* __restrict__ Uh,
                                             unsigned short* __restrict__ Ul) {
    int n = blockIdx.x * 8 + (threadIdx.x >> 5);
    int lane = threadIdx.x & 31;
    if (n >= N_NODES) return;
    float d = dinv[n];
    float dd = d * d;
    float4 self = hw4[(size_t)n * 32 + lane];
    float4 b = bias4[lane];
    float4 acc;
    acc.x = fmaf(dd, self.x, b.x);
    acc.y = fmaf(dd, self.y, b.y);
    acc.z = fmaf(dd, self.z, b.z);
    acc.w = fmaf(dd, self.w, b.w);
    int s0 = rs[n];
    int c = cnt[n];
    int e = 0;
    for (; e + 4 <= c; e += 4) {
        int2 e0 = csr_ew[s0 + e];
        int2 e1 = csr_ew[s0 + e + 1];
        int2 e2 = csr_ew[s0 + e + 2];
        int2 e3 = csr_ew[s0 + e + 3];
        float4 v0 = hw4[(size_t)e0.x * 32 + lane];
        float4 v1 = hw4[(size_t)e1.x * 32 + lane];
        float4 v2 = hw4[(size_t)e2.x * 32 + lane];
        float4 v3 = hw4[(size_t)e3.x * 32 + lane];
        float w0 = __int_as_float(e0.y);
        float w1 = __int_as_float(e1.y);
        float w2 = __int_as_float(e2.y);
        float w3 = __int_as_float(e3.y);
        acc.x = fmaf(w0, v0.x, acc.x); acc.y = fmaf(w0, v0.y, acc.y);
        acc.z = fmaf(w0, v0.z, acc.z); acc.w = fmaf(w0, v0.w, acc.w);
        acc.x = fmaf(w1, v1.x, acc.x); acc.y = fmaf(w1, v1.y, acc.y);
        acc.z = fmaf(w1, v1.z, acc.z); acc.w = fmaf(w1, v1.w, acc.w);
        acc.x = fmaf(w2, v2.x, acc.x); acc.y = fmaf(w2, v2.y, acc.y);
        acc.z = fmaf(w2, v2.z, acc.z); acc.w = fmaf(w2, v2.w, acc.w);
        acc.x = fmaf(w3, v3.x, acc.x); acc.y = fmaf(w3, v3.y, acc.y);
        acc.z = fmaf(w3, v3.z, acc.z); acc.w = fmaf(w3, v3.w, acc.w);
    }
    for (; e < c; e++) {
        int2 ee = csr_ew[s0 + e];
        float4 v = hw4[(size_t)ee.x * 32 + lane];
        float w = __int_as_float(ee.y);
        acc.x = fmaf(w, v.x, acc.x); acc.y = fmaf(w, v.y, acc.y);
        acc.z = fmaf(w, v.z, acc.z); acc.w = fmaf(w, v.w, acc.w);
    }
    ushort4 hv, lv;
    hv.x = f2bf(acc.x); lv.x = f2bf(acc.x - bf2f(hv.x));
    hv.y = f2bf(acc.y); lv.y = f2bf(acc.y - bf2f(hv.y));
    hv.z = f2bf(acc.z); lv.z = f2bf(acc.z - bf2f(hv.z));
    hv.w = f2bf(acc.w); lv.w = f2bf(acc.w - bf2f(hv.w));
    *(ushort4*)(Uh + (size_t)n * 128 + lane * 4) = hv;
    *(ushort4*)(Ul + (size_t)n * 128 + lane * 4) = lv;
}

// ---------------- BN on the hi/lo pair ----------------
__global__ __launch_bounds__(256) void k_bn_stats(const unsigned int* __restrict__ H,
                                                  const unsigned int* __restrict__ L,
                                                  float* __restrict__ sum,
                                                  float* __restrict__ sq) {
    int c = threadIdx.x & 63;   // uint column = features 2c, 2c+1
    int y = threadIdx.x >> 6;
    float s0 = 0.f, s1 = 0.f, q0 = 0.f, q1 = 0.f;
    for (size_t n = (size_t)blockIdx.x * 4 + y; n < N_NODES; n += (size_t)gridDim.x * 4) {
        unsigned int h = H[n * 64 + c], l = L[n * 64 + c];
        float v0 = bf2f(h & 0xffffu) + bf2f(l & 0xffffu);
        float v1 = bf2f(h >> 16) + bf2f(l >> 16);
        s0 += v0; q0 = fmaf(v0, v0, q0);
        s1 += v1; q1 = fmaf(v1, v1, q1);
    }
    __shared__ float ls[256][4];
    ls[threadIdx.x][0] = s0; ls[threadIdx.x][1] = s1;
    ls[threadIdx.x][2] = q0; ls[threadIdx.x][3] = q1;
    __syncthreads();
    if (y == 0) {
#pragma unroll
        for (int yy = 1; yy < 4; yy++) {
            s0 += ls[yy * 64 + c][0]; s1 += ls[yy * 64 + c][1];
            q0 += ls[yy * 64 + c][2]; q1 += ls[yy * 64 + c][3];
        }
        atomicAdd(&sum[2 * c], s0);
        atomicAdd(&sum[2 * c + 1], s1);
        atomicAdd(&sq[2 * c], q0);
        atomicAdd(&sq[2 * c + 1], q1);
    }
}

__global__ void k_bn_finalize(const float* __restrict__ sum, const float* __restrict__ sq,
                              const float* __restrict__ gamma, const float* __restrict__ beta,
                              float* __restrict__ scale, float* __restrict__ shift) {
    int f = threadIdx.x;
    float mu = sum[f] * (1.0f / N_NODES);
    float var = sq[f] * (1.0f / N_NODES) - mu * mu;
    float s = rsqrtf(var + EPS_BN) * gamma[f];
    scale[f] = s;
    shift[f] = beta[f] - mu * s;
}

__global__ __launch_bounds__(256) void k_bn_apply(unsigned int* __restrict__ H,
                                                  unsigned int* __restrict__ L,
                                                  const float* __restrict__ scale,
                                                  const float* __restrict__ shift) {
    size_t i = (size_t)blockIdx.x * 256 + threadIdx.x;  // N_NODES*64 uints
    int c = (int)(i & 63);
    unsigned int h = H[i], l = L[i];
    float v0 = bf2f(h & 0xffffu) + bf2f(l & 0xffffu);
    float v1 = bf2f(h >> 16) + bf2f(l >> 16);
    v0 = fmaxf(fmaf(v0, scale[2 * c], shift[2 * c]), 0.f);
    v1 = fmaxf(fmaf(v1, scale[2 * c + 1], shift[2 * c + 1]), 0.f);
    unsigned short h0 = f2bf(v0), h1 = f2bf(v1);
    unsigned short l0 = f2bf(v0 - bf2f(h0)), l1 = f2bf(v1 - bf2f(h1));
    H[i] = (unsigned int)h0 | ((unsigned int)h1 << 16);
    L[i] = (unsigned int)l0 | ((unsigned int)l1 << 16);
}

// ---------------- pooling + decoder ----------------
__global__ void k_gcount(const int* __restrict__ batch, int* __restrict__ gcnt) {
    int n = blockIdx.x * 256 + threadIdx.x;
    if (n < N_NODES) atomicAdd(&gcnt[batch[n]], 1);
}

__global__ void k_gscan(const int* __restrict__ gcnt, int* __restrict__ gstart) {
    __shared__ int s[256];
    int t = threadIdx.x;
    int v = gcnt[t];
    s[t] = v;
    __syncthreads();
    for (int off = 1; off < 256; off <<= 1) {
        int x = 0;
        if (t >= off) x = s[t - off];
        __syncthreads();
        if (t >= off) s[t] += x;
        __syncthreads();
    }
    gstart[t] = s[t] - v;
}

__global__ __launch_bounds__(256) void k_pool(const float* __restrict__ encp,
                                              const float* __restrict__ eb,
                                              const int* __restrict__ gstart,
                                              const int* __restrict__ gcnt,
                                              float* __restrict__ pooled) {
    int g = blockIdx.x;
    int f = threadIdx.x;
    int s0 = gstart[g];
    int c = gcnt[g];
    float b = eb[f];
    float acc = 0.f;
    for (int i = 0; i < c; i++) {
        float v = encp[(size_t)(s0 + i) * ENCDIM + f] + b;
        acc += fmaxf(v, 0.f);
    }
    pooled[g * ENCDIM + f] = acc / fmaxf((float)c, 1.0f);
}

__global__ __launch_bounds__(128) void k_dec(const float* __restrict__ pooled,
                                             const float* __restrict__ W1,
                                             const float* __restrict__ b1,
                                             const float* __restrict__ W2,
                                             const float* __restrict__ b2,
                                             float* __restrict__ out) {
    int g = blockIdx.x;
    int j = threadIdx.x;
    const float* p = &pooled[g * ENCDIM];
    float acc = b1[j];
    for (int k = 0; k < ENCDIM; k++) acc = fmaf(p[k], W1[k * 128 + j], acc);
    float h = fmaxf(acc, 0.f) * W2[j];
    for (int off = 32; off; off >>= 1) h += __shfl_down(h, off);
    __shared__ float red[2];
    if ((j & 63) == 0) red[j >> 6] = h;
    __syncthreads();
    if (j == 0) out[g] = red[0] + red[1] + b2[0];
}

extern "C" void kernel_launch(void* const* d_in, const int* in_sizes, int n_in,
                              void* d_out, int out_size, void* d_ws, size_t ws_size,
                              hipStream_t stream) {
    const float* x = (const float*)d_in[0];
    const int* ei = (const int*)d_in[1];
    const int* src = ei;
    const int* dst = ei + N_EDGES;
    const int* batch = (const int*)d_in[2];
    const float* convW = (const float*)d_in[3];
    const float* convB = (const float*)d_in[4];
    const float* gamma = (const float*)d_in[5];
    const float* beta = (const float*)d_in[6];
    const float* encW = (const float*)d_in[7];
    const float* encB = (const float*)d_in[8];
    const float* dW1 = (const float*)d_in[9];
    const float* db1 = (const float*)d_in[10];
    const float* dW2 = (const float*)d_in[11];
    const float* db2 = (const float*)d_in[12];
    float* out = (float*)d_out;

    char* w = (char*)d_ws;
    auto alloc = [&](size_t bytes) {
        char* p = w;
        w += (bytes + 255) & ~(size_t)255;
        return p;
    };
    int* cnt = (int*)alloc((size_t)N_NODES * 4);
    int* rs = (int*)alloc((size_t)N_NODES * 4);
    int* cursor = (int*)alloc((size_t)N_NODES * 4);
    int* bsums = (int*)alloc(512 * 4);
    float* dinv = (float*)alloc((size_t)N_NODES * 4);
    int2* csr_ew = (int2*)alloc((size_t)N_EDGES * 8);
    unsigned short* Uh = (unsigned short*)alloc((size_t)NPAD * 128 * 2);
    unsigned short* Ul = (unsigned short*)alloc((size_t)NPAD * 128 * 2);
    float* B = (float*)alloc((size_t)NPAD * HDIM * 4);          // hw fp32
    float* encp = (float*)alloc((size_t)NPAD * ENCDIM * 4);     // encoder pre-act
    unsigned short* convWfh = (unsigned short*)alloc((size_t)NLAYERS * 16384 * 2);
    unsigned short* convWfl = (unsigned short*)alloc((size_t)NLAYERS * 16384 * 2);
    unsigned short* encWfh = (unsigned short*)alloc((size_t)NLAYERS * 32768 * 2);
    unsigned short* encWfl = (unsigned short*)alloc((size_t)NLAYERS * 32768 * 2);
    float* bnsum = (float*)alloc(128 * 4);
    float* bnsq = (float*)alloc(128 * 4);
    float* bnscale = (float*)alloc(128 * 4);
    float* bnshift = (float*)alloc(128 * 4);
    int* gcnt = (int*)alloc(256 * 4);
    int* gstart = (int*)alloc(256 * 4);
    float* pooled = (float*)alloc(256 * 256 * 4);

    // CSR build + degree normalization
    hipMemsetAsync(cnt, 0, (size_t)N_NODES * 4, stream);
    k_count<<<(N_EDGES + 255) / 256, 256, 0, stream>>>(dst, cnt);
    k_dinv<<<(N_NODES + 255) / 256, 256, 0, stream>>>(cnt, dinv);
    int nb = (N_NODES + 255) / 256;  // 391
    k_scan_block<<<nb, 256, 0, stream>>>(cnt, rs, bsums);
    k_scan_sums<<<1, 512, 0, stream>>>(bsums, nb);
    k_scan_add<<<nb, 256, 0, stream>>>(rs, bsums, cursor);
    k_scatter<<<(N_EDGES + 255) / 256, 256, 0, stream>>>(src, dst, dinv, cursor, csr_ew);

    // weight fragment permute + split (tiny)
    for (int l = 0; l < NLAYERS; l++) {
        k_wfrag<<<8, 256, 0, stream>>>(convW + (size_t)l * 16384, 128, 8,
                                       convWfh + (size_t)l * 16384,
                                       convWfl + (size_t)l * 16384);
        k_wfrag<<<16, 256, 0, stream>>>(encW + (size_t)l * 128 * 256, 256, 16,
                                        encWfh + (size_t)l * 32768,
                                        encWfl + (size_t)l * 32768);
    }

    // x -> U pair (pads zeroed)
    k_split_x<<<NPAD * 32 / 256, 256, 0, stream>>>((const float4*)x, (ushort4*)Uh,
                                                   (ushort4*)Ul);

    for (int l = 0; l < NLAYERS; l++) {
        // hw = h @ convW_l
        k_mfma<0><<<dim3(NPAD / 128, 1), 256, 0, stream>>>(
            Uh, Ul, convWfh + (size_t)l * 16384, convWfl + (size_t)l * 16384, B, 128);
        // aggregate + bias -> U pair
        k_agg<<<N_NODES / 8, 256, 0, stream>>>((const float4*)B, rs, cnt, csr_ew, dinv,
                                               (const float4*)(convB + l * 128), Uh, Ul);
        // BN + ReLU on U pair
        hipMemsetAsync(bnsum, 0, 128 * 4, stream);
        hipMemsetAsync(bnsq, 0, 128 * 4, stream);
        k_bn_stats<<<512, 256, 0, stream>>>((const unsigned int*)Uh,
                                            (const unsigned int*)Ul, bnsum, bnsq);
        k_bn_finalize<<<1, 128, 0, stream>>>(bnsum, bnsq, gamma + l * 128, beta + l * 128,
                                             bnscale, bnshift);
        k_bn_apply<<<N_NODES * 64 / 256, 256, 0, stream>>>((unsigned int*)Uh,
                                                           (unsigned int*)Ul,
                                                           bnscale, bnshift);
        // encp (+)= h_l @ encW_l
        if (l == 0)
            k_mfma<0><<<dim3(NPAD / 128, 2), 256, 0, stream>>>(
                Uh, Ul, encWfh + (size_t)l * 32768, encWfl + (size_t)l * 32768, encp, 256);
        else
            k_mfma<1><<<dim3(NPAD / 128, 2), 256, 0, stream>>>(
                Uh, Ul, encWfh + (size_t)l * 32768, encWfl + (size_t)l * 32768, encp, 256);
    }

    // pooling (batch is sorted)
    hipMemsetAsync(gcnt, 0, 256 * 4, stream);
    k_gcount<<<(N_NODES + 255) / 256, 256, 0, stream>>>(batch, gcnt);
    k_gscan<<<1, 256, 0, stream>>>(gcnt, gstart);
    k_pool<<<256, 256, 0, stream>>>(encp, encB, gstart, gcnt, pooled);
    k_dec<<<256, 128, 0, stream>>>(pooled, dW1, db1, dW2, db2, out);
}